// Round 6
// baseline (49.866 us; speedup 1.0000x reference)
//
#include <hip/hip_runtime.h>

#define FG_THRESH 0.7f
#define BG_HI 0.5f
#define BG_LO 0.1f
#define BATCH 256
#define FG_ROIS 128
#define KGT 256
#define CLS 81
#define CPT 5                      // mask words per thread (covers NCH<=1280)
#define NCHPAD 1280

// ---------------------------------------------------------------------------
// A: IoU max/argmax. 4 lanes per roi (lane covers k = c mod 4), exact IEEE
//    division, first-of-max merge via shfl butterfly (bit-validated r1-r5).
//    One 64-roi chunk per block.
// ---------------------------------------------------------------------------
__global__ __launch_bounds__(256) void k_iou(
    const float* __restrict__ proposals,   // (N,4)
    const float* __restrict__ gt_boxes,    // (K,4)
    int N, int M,
    int* __restrict__ gt_assign,           // [M]
    unsigned long long* __restrict__ fgm,  // [NCH]
    unsigned long long* __restrict__ bgm,  // [NCH]
    unsigned long long* __restrict__ nbm)  // [NCH]
{
    __shared__ float4 gsh[KGT];
    __shared__ float garea[KGT];
    __shared__ unsigned int wm[3][4];

    int tid = threadIdx.x;
    {
        float4 g = ((const float4*)gt_boxes)[tid];
        gsh[tid] = g;
        garea[tid] = (g.z - g.x + 1.0f) * (g.w - g.y + 1.0f);
    }
    __syncthreads();

    int wv = tid >> 6, lane = tid & 63;
    int c = lane & 3;          // k-class (k mod 4)
    int rj = lane >> 2;        // roi within wave, 0..15
    int roi = blockIdx.x * 64 + wv * 16 + rj;

    float best = -1.0f;
    int bestk = 0;
    {
        float4 a;
        if (roi < M) a = (roi < N) ? ((const float4*)proposals)[roi]
                                   : gsh[roi - N];
        else         a = gsh[0];               // dummy, masked below
        float area_a = (a.z - a.x + 1.0f) * (a.w - a.y + 1.0f);
        #pragma unroll 4
        for (int j = 0; j < KGT / 4; ++j) {
            int k = (j << 2) | c;
            float4 g = gsh[k];
            float x1 = fmaxf(a.x, g.x);
            float y1 = fmaxf(a.y, g.y);
            float x2 = fminf(a.z, g.z);
            float y2 = fminf(a.w, g.w);
            float iw = fmaxf(x2 - x1 + 1.0f, 0.0f);
            float ih = fmaxf(y2 - y1 + 1.0f, 0.0f);
            float inter = iw * ih;
            float ov = inter / (area_a + garea[k] - inter);  // IEEE div = np
            if (ov > best) { best = ov; bestk = k; }
        }
    }
    #pragma unroll
    for (int d = 1; d < 4; d <<= 1) {
        float ob = __shfl_xor(best, d);
        int   kb = __shfl_xor(bestk, d);
        if (ob > best || (ob == best && kb < bestk)) { best = ob; bestk = kb; }
    }
    float bset = __shfl(best, (lane & 15) * 4);
    int   bk   = __shfl(bestk, (lane & 15) * 4);

    int roi2 = blockIdx.x * 64 + wv * 16 + (lane & 15);
    bool isv = (lane < 16) && (roi2 < M);
    bool fgp = isv && (bset >= FG_THRESH);
    bool bgp = isv && (bset < BG_HI) && (bset >= BG_LO);
    bool nbp = isv && !bgp;
    if (isv) gt_assign[roi2] = bk;

    unsigned int mf = (unsigned int)(__ballot(fgp) & 0xFFFFull);
    unsigned int mb = (unsigned int)(__ballot(bgp) & 0xFFFFull);
    unsigned int mn = (unsigned int)(__ballot(nbp) & 0xFFFFull);
    if (lane == 0) { wm[0][wv] = mf; wm[1][wv] = mb; wm[2][wv] = mn; }
    __syncthreads();
    if (tid == 0) {
        fgm[blockIdx.x] = (unsigned long long)wm[0][0]        | ((unsigned long long)wm[0][1] << 16)
                        | ((unsigned long long)wm[0][2] << 32) | ((unsigned long long)wm[0][3] << 48);
        bgm[blockIdx.x] = (unsigned long long)wm[1][0]        | ((unsigned long long)wm[1][1] << 16)
                        | ((unsigned long long)wm[1][2] << 32) | ((unsigned long long)wm[1][3] << 48);
        nbm[blockIdx.x] = (unsigned long long)wm[2][0]        | ((unsigned long long)wm[2][1] << 16)
                        | ((unsigned long long)wm[2][2] << 32) | ((unsigned long long)wm[2][3] << 48);
    }
}

// ---------------------------------------------------------------------------
// B: 81 blocks. Coalesced LDS mask staging -> blocked scan/extract (as r5) ->
//    wave-per-pos meta with ballot-based one-hot cls -> computed (not
//    gathered) label writes + bbox float4 writes. Block 0 writes rois.
// ---------------------------------------------------------------------------
__global__ __launch_bounds__(256) void k_finish(
    const float* __restrict__ proposals,
    const float* __restrict__ gt_boxes,
    const float* __restrict__ gt_labels,   // (K,C) one-hot rows
    int N, int NCH,
    const int* __restrict__ gt_assign,
    const unsigned long long* __restrict__ fgm,
    const unsigned long long* __restrict__ bgm,
    const unsigned long long* __restrict__ nbm,
    float* __restrict__ out_rois,          // (BATCH,4)
    float* __restrict__ out_labels,        // (BATCH*CLS)
    float4* __restrict__ out_bbox)         // (BATCH*CLS) float4 slots
{
    __shared__ unsigned long long sf[NCHPAD], sb[NCHPAD], sn[NCHPAD];
    __shared__ int fgl[FG_ROIS], bgl[BATCH], nbl[BATCH];
    __shared__ int wtot[3][4];
    __shared__ int lm_cls[8];
    __shared__ float4 lm_t[8];

    int tid = threadIdx.x;
    int lane = tid & 63, wv = tid >> 6;

    // coalesced LDS staging (pad words zeroed)
    for (int idx = tid; idx < NCHPAD; idx += 256) {
        bool v = (idx < NCH);
        sf[idx] = v ? fgm[idx] : 0ull;
        sb[idx] = v ? bgm[idx] : 0ull;
        sn[idx] = v ? nbm[idx] : 0ull;
    }
    __syncthreads();

    // blocked ownership: thread t owns words [5t, 5t+5)
    int lo = tid * CPT;
    unsigned long long wf[CPT], wb[CPT], wn[CPT];
    #pragma unroll
    for (int r = 0; r < CPT; ++r) {
        wf[r] = sf[lo + r];
        wb[r] = sb[lo + r];
        wn[r] = sn[lo + r];
    }
    int pc0 = 0, pc1 = 0, pc2 = 0;
    #pragma unroll
    for (int r = 0; r < CPT; ++r) {
        pc0 += __popcll(wf[r]);
        pc1 += __popcll(wb[r]);
        pc2 += __popcll(wn[r]);
    }

    // wave inclusive scan, then cross-wave offsets
    int i0 = pc0, i1 = pc1, i2 = pc2;
    #pragma unroll
    for (int d = 1; d < 64; d <<= 1) {
        int t0 = __shfl_up(i0, d);
        int t1 = __shfl_up(i1, d);
        int t2 = __shfl_up(i2, d);
        if (lane >= d) { i0 += t0; i1 += t1; i2 += t2; }
    }
    if (lane == 63) { wtot[0][wv] = i0; wtot[1][wv] = i1; wtot[2][wv] = i2; }
    __syncthreads();
    int o0 = 0, o1 = 0, o2 = 0;
    for (int x = 0; x < wv; ++x) { o0 += wtot[0][x]; o1 += wtot[1][x]; o2 += wtot[2][x]; }
    int b0 = o0 + i0 - pc0;      // exclusive prefix
    int b1 = o1 + i1 - pc1;
    int b2 = o2 + i2 - pc2;
    int num_fg = wtot[0][0] + wtot[0][1] + wtot[0][2] + wtot[0][3];
    int num_bg = wtot[1][0] + wtot[1][1] + wtot[1][2] + wtot[1][3];

    // ordered extraction: first FG_ROIS fg / BATCH bg / BATCH nonbg
    #pragma unroll
    for (int r = 0; r < CPT; ++r) {
        int w = lo + r;
        unsigned long long m = wf[r];
        while (m && b0 < FG_ROIS) { fgl[b0++] = (w << 6) + __ffsll(m) - 1; m &= m - 1; }
        m = wb[r];
        while (m && b1 < BATCH)   { bgl[b1++] = (w << 6) + __ffsll(m) - 1; m &= m - 1; }
        m = wn[r];
        while (m && b2 < BATCH)   { nbl[b2++] = (w << 6) + __ffsll(m) - 1; m &= m - 1; }
    }
    __syncthreads();

    int fg_take = min(FG_ROIS, num_fg);
    int eBase = blockIdx.x * 256;
    int posLo = eBase / CLS;
    int posHi = (eBase + 255) / CLS;
    int np = posHi - posLo + 1;            // <= 5

    // per-slot meta: wave wv handles slots wv, wv+4 (all lanes cooperate)
    for (int s = wv; s < np; s += 4) {
        int pos = posLo + s;
        int is_fg = (pos < fg_take) ? 1 : 0;
        int j = pos - fg_take;
        int keep = is_fg ? fgl[pos] : ((j < num_bg) ? bgl[j] : nbl[j - num_bg]);
        float4 a = (keep < N) ? ((const float4*)proposals)[keep]
                              : ((const float4*)gt_boxes)[keep - N];   // broadcast
        int ga = gt_assign[keep];                                       // broadcast
        float4 g = ((const float4*)gt_boxes)[ga];                       // broadcast

        float ew = a.z - a.x + 1.0f, eh = a.w - a.y + 1.0f;
        float ecx = a.x + 0.5f * ew, ecy = a.y + 0.5f * eh;
        float gw = g.z - g.x + 1.0f, gh = g.w - g.y + 1.0f;
        float gcx = g.x + 0.5f * gw, gcy = g.y + 0.5f * gh;

        int cls = 0;
        if (is_fg) {
            // one-hot argmax via ballot: lane covers classes lane, lane+64
            float l1 = gt_labels[(size_t)ga * CLS + lane];
            int c2 = lane + 64;
            float l2 = (c2 < CLS) ? gt_labels[(size_t)ga * CLS + c2] : 0.0f;
            unsigned long long m1 = __ballot(l1 > 0.5f);
            unsigned long long m2 = __ballot(c2 < CLS && l2 > 0.5f);
            cls = m1 ? (__ffsll(m1) - 1) : (m2 ? 64 + __ffsll(m2) - 1 : 0);
        }
        if (lane == 0) {
            lm_cls[s] = cls;   // cls==0 for bg slots -> exact one-hot(0) row
            lm_t[s] = make_float4((gcx - ecx) / ew, (gcy - ecy) / eh,
                                  logf(gw / ew), logf(gh / eh));
        }
    }

    // block 0: rois output (one gather per thread)
    if (blockIdx.x == 0) {
        int pos = tid;
        int is_fg = (pos < fg_take) ? 1 : 0;
        int j = pos - fg_take;
        int keep = is_fg ? fgl[pos] : ((j < num_bg) ? bgl[j] : nbl[j - num_bg]);
        float4 a = (keep < N) ? ((const float4*)proposals)[keep]
                              : ((const float4*)gt_boxes)[keep - N];
        ((float4*)out_rois)[pos] = a;
    }
    __syncthreads();

    // this block's 256 label elements + 256 bbox float4 slots (computed)
    int e = eBase + tid;
    int pos = e / CLS, cc = e - pos * CLS;
    int li = pos - posLo;
    int cl = lm_cls[li];
    out_labels[e] = (cc == cl) ? 1.0f : 0.0f;
    out_bbox[e] = (cl > 0 && cc == cl) ? lm_t[li]
                                       : make_float4(0.f, 0.f, 0.f, 0.f);
}

// ---------------------------------------------------------------------------
extern "C" void kernel_launch(void* const* d_in, const int* in_sizes, int n_in,
                              void* d_out, int out_size, void* d_ws, size_t ws_size,
                              hipStream_t stream)
{
    const float* proposals = (const float*)d_in[0];
    const float* gt_labels = (const float*)d_in[1];
    const float* gt_boxes  = (const float*)d_in[2];
    int N = in_sizes[0] / 4;           // 80000
    int K = in_sizes[2] / 4;           // 256
    int M = N + K;                     // 80256
    int NCH = (M + 63) / 64;           // 1254

    char* ws = (char*)d_ws;
    size_t off = 0;
    auto alloc = [&](size_t bytes) -> void* {
        void* p = ws + off;
        off += (bytes + 255) & ~(size_t)255;
        return p;
    };
    int* gt_assign = (int*)alloc((size_t)M * 4);
    unsigned long long* fgm = (unsigned long long*)alloc((size_t)NCH * 8);
    unsigned long long* bgm = (unsigned long long*)alloc((size_t)NCH * 8);
    unsigned long long* nbm = (unsigned long long*)alloc((size_t)NCH * 8);

    float* out_rois   = (float*)d_out;
    float* out_labels = out_rois + BATCH * 4;
    float4* out_bbox  = (float4*)(out_labels + BATCH * CLS);

    k_iou<<<NCH, 256, 0, stream>>>(proposals, gt_boxes, N, M,
                                   gt_assign, fgm, bgm, nbm);
    int nb2 = (BATCH * CLS) / 256;     // 81 exact
    k_finish<<<nb2, 256, 0, stream>>>(proposals, gt_boxes, gt_labels, N, NCH,
                                      gt_assign, fgm, bgm, nbm,
                                      out_rois, out_labels, out_bbox);
    (void)K; (void)n_in; (void)out_size; (void)ws_size;
}